// Round 2
// baseline (870.344 us; speedup 1.0000x reference)
//
#include <hip/hip_runtime.h>
#include <math.h>

// ---------------------------------------------------------------------------
// voting / segment-mean / argmax — two-phase deterministic reduction
// shapes (fixed dataset): B=512, T=50, N=6400, L=10
// ws layout: s f32[B*N] | partial f64[G*L*N] | counts int[L]
// No global atomics in the value path (R1 lesson: 3.3M f64 atomics -> 843us).
// ---------------------------------------------------------------------------

#define LBL 10   // n_labels, fixed for this dataset
#define GRP 8    // b-groups in phase 2 (512/8 = 64 samples per group)

// Phase 1: s[b][n] = sum_t spikes[b][t][n]. Pure streaming, float4, no atomics.
__global__ void tsum_k(const float* __restrict__ spikes,
                       float* __restrict__ s, int T, int N) {
    const int b = blockIdx.y;
    const int v = blockIdx.x * blockDim.x + threadIdx.x;  // float4 index
    const int V = N >> 2;
    if (v >= V) return;
    const float4* p = (const float4*)(spikes + (size_t)b * T * N) + v;
    float4 a = {0.f, 0.f, 0.f, 0.f};
#pragma unroll 5
    for (int t = 0; t < T; ++t) {
        float4 x = p[(size_t)t * V];
        a.x += x.x; a.y += x.y; a.z += x.z; a.w += x.w;
    }
    ((float4*)(s + (size_t)b * N))[v] = a;
}

// Counts: one block, LDS histogram, deterministic, no global pre-zero needed.
__global__ void count_k(const int* __restrict__ labels, int* __restrict__ counts,
                        int B) {
    __shared__ int h[16];
    if (threadIdx.x < LBL) h[threadIdx.x] = 0;
    __syncthreads();
    for (int b = threadIdx.x; b < B; b += blockDim.x)
        atomicAdd(&h[labels[b]], 1);
    __syncthreads();
    if (threadIdx.x < LBL) counts[threadIdx.x] = h[threadIdx.x];
}

// Phase 2: per-label partial sums over a 64-sample b-range, double registers.
// labels[b] is wave-uniform -> scalar compare chain, no register indexing.
__global__ void seg_k(const float* __restrict__ s, const int* __restrict__ labels,
                      double* __restrict__ partial, int N, int BG) {
    const int n = blockIdx.x * blockDim.x + threadIdx.x;
    if (n >= N) return;
    const int b0 = blockIdx.y * BG;
    double acc[LBL];
#pragma unroll
    for (int l = 0; l < LBL; ++l) acc[l] = 0.0;
    for (int b = b0; b < b0 + BG; ++b) {
        const int lab = labels[b];                 // uniform -> s_load
        const float v = s[(size_t)b * N + n];      // coalesced across n
#pragma unroll
        for (int l = 0; l < LBL; ++l)
            acc[l] += (lab == l) ? (double)v : 0.0;
    }
#pragma unroll
    for (int l = 0; l < LBL; ++l)
        partial[((size_t)blockIdx.y * LBL + l) * N + n] = acc[l];
}

// Finalize: sum partials -> mean -> rates_new -> first-max argmax.
__global__ void finalize_k(const double* __restrict__ partial,
                           const int* __restrict__ counts,
                           const float* __restrict__ rates,
                           float* __restrict__ out, int N) {
    const int n = blockIdx.x * blockDim.x + threadIdx.x;
    if (n >= N) return;
    float best = -INFINITY;
    int bi = 0;
#pragma unroll
    for (int l = 0; l < LBL; ++l) {
        double sv = 0.0;
#pragma unroll
        for (int g = 0; g < GRP; ++g)
            sv += partial[((size_t)g * LBL + l) * N + n];
        const int c = counts[l];
        const float r = rates[(size_t)n * LBL + l];
        // ALPHA = 1.0; update only where label present in batch
        const float val = (c > 0) ? (r + (float)(sv / (double)c)) : r;
        out[(size_t)N + (size_t)n * LBL + l] = val;
        if (val > best) { best = val; bi = l; }   // strict > => first max
    }
    out[n] = (float)bi;
}

extern "C" void kernel_launch(void* const* d_in, const int* in_sizes, int n_in,
                              void* d_out, int out_size, void* d_ws, size_t ws_size,
                              hipStream_t stream) {
    const float* spikes = (const float*)d_in[0];
    const int*   labels = (const int*)d_in[1];
    const float* rates  = (const float*)d_in[2];
    const int B = in_sizes[1];
    const int N = in_sizes[2] / LBL;
    const int T = in_sizes[0] / (B * N);
    float* out = (float*)d_out;

    // ws carve-up (≈17.3 MB; ws is 2.6 GB)
    float*  s       = (float*)d_ws;
    size_t  s_bytes = (size_t)B * N * sizeof(float);
    double* partial = (double*)((char*)d_ws + s_bytes);
    size_t  p_bytes = (size_t)GRP * LBL * N * sizeof(double);
    int*    counts  = (int*)((char*)d_ws + s_bytes + p_bytes);

    // K1: streaming T-sum (the only HBM-scale kernel)
    {
        const int V = N >> 2;
        const int th = 256;
        dim3 g((V + th - 1) / th, B);
        tsum_k<<<g, dim3(th), 0, stream>>>(spikes, s, T, N);
    }
    // K2: label counts
    count_k<<<dim3(1), dim3(512), 0, stream>>>(labels, counts, B);
    // K3: segment partial sums (deterministic, no atomics)
    {
        const int th = 256;
        dim3 g((N + th - 1) / th, GRP);
        seg_k<<<g, dim3(th), 0, stream>>>(s, labels, partial, N, B / GRP);
    }
    // K4: finalize
    {
        const int th = 256;
        finalize_k<<<dim3((N + th - 1) / th), dim3(th), 0, stream>>>(
            partial, counts, rates, out, N);
    }
}